// Round 6
// baseline (87.420 us; speedup 1.0000x reference)
//
#include <hip/hip_runtime.h>
#include <hip/hip_bf16.h>
#include <math.h>

#define BN_EPS 1e-5f

typedef __attribute__((ext_vector_type(8))) short short8;
typedef __attribute__((ext_vector_type(4))) float f32x4;

__device__ __forceinline__ unsigned short bfbits(float f) {
  __hip_bfloat16 h = __float2bfloat16(f);           // HW RNE convert
  return *reinterpret_cast<unsigned short*>(&h);
}
__device__ __forceinline__ float bf2f(unsigned short u) {
  union { unsigned v; float f; } c; c.v = ((unsigned)u) << 16;
  return c.f;
}

// ---------------- Kernel A: fused prep (blocks 0..15) + pool (blocks 16..) ----
// prep: A_s = sc3*W_s + conv_taps, split bf16 hi/lo; totb[4].
// pool: global average over H,W per (b,c) plane.
__global__ __launch_bounds__(256) void prep_pool_kernel(
    const float* __restrict__ x, float* __restrict__ pooled,
    const float* __restrict__ fc3_w,
    const float* __restrict__ g3, const float* __restrict__ b3,
    const float* __restrict__ m3, const float* __restrict__ v3,
    const float* __restrict__ c1w,
    const float* __restrict__ g1, const float* __restrict__ b1,
    const float* __restrict__ m1, const float* __restrict__ v1,
    const float* __restrict__ c3w,
    const float* __restrict__ gk, const float* __restrict__ bk,
    const float* __restrict__ mk, const float* __restrict__ vk,
    unsigned short* __restrict__ ahi, unsigned short* __restrict__ alo,
    float* __restrict__ totb) {
  int bid = blockIdx.x;
  int tid = threadIdx.x;
  if (bid < 16) {
    int s = bid >> 2;
    int o = (bid & 3) * 16 + (tid >> 4);
    int kc = (tid & 15) * 4;
    float sc3 = g3[s] * rsqrtf(v3[s] + BN_EPS);
    float sc1 = g1[s] * rsqrtf(v1[s] + BN_EPS);
    float sck = gk[s] * rsqrtf(vk[s] + BN_EPS);
    float c0 = sc1 * c1w[s] + sck * c3w[s * 9 + 4];
    int oh = o >> 3, ow = o & 7;
    unsigned short H[4], L[4];
#pragma unroll
    for (int j = 0; j < 4; ++j) {
      int k = kc + j;
      int kh = k >> 3, kw = k & 7;
      float a = sc3 * fc3_w[(s * 64 + o) * 64 + k];
      int dy = kh - oh, dx = kw - ow;
      if (dy >= -1 && dy <= 1 && dx >= -1 && dx <= 1)
        a += (dy == 0 && dx == 0) ? c0 : sck * c3w[s * 9 + (dy + 1) * 3 + (dx + 1)];
      unsigned short h = bfbits(a);
      H[j] = h;
      L[j] = bfbits(a - bf2f(h));
    }
    size_t base = (size_t)(s * 64 + o) * 64 + kc;
    *(ushort4*)(ahi + base) = make_ushort4(H[0], H[1], H[2], H[3]);
    *(ushort4*)(alo + base) = make_ushort4(L[0], L[1], L[2], L[3]);
    if (bid == 0 && tid < 4) {
      int ss = tid;
      float s3 = g3[ss] * rsqrtf(v3[ss] + BN_EPS);
      float s1 = g1[ss] * rsqrtf(v1[ss] + BN_EPS);
      float sk = gk[ss] * rsqrtf(vk[ss] + BN_EPS);
      totb[ss] = (b3[ss] - m3[ss] * s3) + (b1[ss] - m1[ss] * s1) + (bk[ss] - mk[ss] * sk);
    }
    return;
  }
  int bc = bid - 16;
  const float4* xp = reinterpret_cast<const float4*>(x + (size_t)bc * 4096);
  float s = 0.f;
#pragma unroll
  for (int k = 0; k < 4; ++k) {
    float4 v = xp[k * 256 + tid];
    s += (v.x + v.y) + (v.z + v.w);
  }
#pragma unroll
  for (int m = 32; m >= 1; m >>= 1) s += __shfl_xor(s, m, 64);
  __shared__ float wsum[4];
  if ((tid & 63) == 0) wsum[tid >> 6] = s;
  __syncthreads();
  if (tid == 0) pooled[bc] = (wsum[0] + wsum[1] + wsum[2] + wsum[3]) * (1.f / 4096.f);
}

// ---------------- Kernel B: gate MLP ----------------
__global__ __launch_bounds__(256) void gate_kernel(const float* __restrict__ pooled,
                                                   const float* __restrict__ fc1_w,
                                                   const float* __restrict__ fc1_b,
                                                   const float* __restrict__ fc2_w,
                                                   const float* __restrict__ fc2_b,
                                                   float* __restrict__ gate) {
  int b = blockIdx.x;
  int tid = threadIdx.x;
  __shared__ float p[256];
  __shared__ float hbuf[64];
  p[tid] = pooled[b * 256 + tid];
  __syncthreads();
  if (tid < 64) {
    float a = fc1_b[tid];
    const float* wr = fc1_w + tid * 256;
#pragma unroll 8
    for (int c = 0; c < 256; ++c) a += p[c] * wr[c];
    hbuf[tid] = fmaxf(a, 0.f);
  }
  __syncthreads();
  float g = fc2_b[tid];
  const float* w2 = fc2_w + tid * 64;
#pragma unroll 8
  for (int j = 0; j < 64; ++j) g += hbuf[j] * w2[j];
  gate[b * 256 + tid] = 1.f / (1.f + expf(-g));
}

// ---------------- Kernel C: main — Y = (A_s @ X + totb) * gate ----------
// Grid (b, hpi, cgh, sp): 4096 blocks. Block = 4 waves = (2 s) x (2 o-halves).
// Per-thread state halved vs R5 (A 32, acc 32) -> 4 waves/SIMD occupancy.
__global__ __launch_bounds__(256, 4) void main_kernel(
    const float* __restrict__ x,
    const unsigned short* __restrict__ ahi, const unsigned short* __restrict__ alo,
    const float* __restrict__ totb, const float* __restrict__ gate,
    float* __restrict__ out) {
  int bid = blockIdx.x;
  int sp  = bid & 1;
  int cgh = (bid >> 1) & 7;
  int hpi = (bid >> 4) & 7;
  int b   = bid >> 7;
  int tid = threadIdx.x;
  int s    = __builtin_amdgcn_readfirstlane(sp * 2 + ((tid >> 7) & 1));
  int half = __builtin_amdgcn_readfirstlane((tid >> 6) & 1);
  int r16 = tid & 15;
  int g   = (tid >> 4) & 3;

  float tb = totb[s];

  // A fragments: rows o = (half*2+oti)*16 + r16
  short8 Ah[2][2], Al[2][2];  // [kt][oti]
#pragma unroll
  for (int oti = 0; oti < 2; ++oti)
#pragma unroll
    for (int kt = 0; kt < 2; ++kt) {
      size_t off = (size_t)(s * 64 + (half * 2 + oti) * 16 + r16) * 64 + kt * 32 + g * 8;
      Ah[kt][oti] = *(const short8*)(ahi + off);
      Al[kt][oti] = *(const short8*)(alo + off);
    }

  f32x4 acc[2][4];
#pragma unroll
  for (int i = 0; i < 2; ++i)
#pragma unroll
    for (int j = 0; j < 4; ++j) acc[i][j] = f32x4{0.f, 0.f, 0.f, 0.f};

#pragma unroll
  for (int kt = 0; kt < 2; ++kt) {
    // batch-issue all 8 dwordx4 loads for this kt before any use
    f32x4 q0[4], q1[4];
#pragma unroll
    for (int nt = 0; nt < 4; ++nt) {
      int n2 = nt * 16 + r16;
      int c_in = (cgh * 8 + (n2 & 7)) * 4 + s;
      const float* bp = x + (size_t)(b * 256 + c_in) * 4096
                        + (hpi * 8 + kt * 4 + g) * 64 + (n2 >> 3) * 8;
      q0[nt] = *(const f32x4*)bp;
      q1[nt] = *(const f32x4*)(bp + 4);
    }
#pragma unroll
    for (int nt = 0; nt < 4; ++nt) {
      float fv[8] = {q0[nt].x, q0[nt].y, q0[nt].z, q0[nt].w,
                     q1[nt].x, q1[nt].y, q1[nt].z, q1[nt].w};
      union { unsigned short u[8]; short8 v; } BH, BL;
#pragma unroll
      for (int j = 0; j < 8; ++j) {
        unsigned short h = bfbits(fv[j]);
        BH.u[j] = h;
        BL.u[j] = bfbits(fv[j] - bf2f(h));
      }
#pragma unroll
      for (int oti = 0; oti < 2; ++oti) {
        acc[oti][nt] = __builtin_amdgcn_mfma_f32_16x16x32_bf16(Ah[kt][oti], BH.v, acc[oti][nt], 0, 0, 0);
        acc[oti][nt] = __builtin_amdgcn_mfma_f32_16x16x32_bf16(Ah[kt][oti], BL.v, acc[oti][nt], 0, 0, 0);
        acc[oti][nt] = __builtin_amdgcn_mfma_f32_16x16x32_bf16(Al[kt][oti], BH.v, acc[oti][nt], 0, 0, 0);
      }
    }
  }

  // epilogue: acc[oti][nt] reg r -> o = (half*2+oti)*16 + g*4 + r, col n2
#pragma unroll
  for (int nt = 0; nt < 4; ++nt) {
    int n2 = nt * 16 + r16;
    int c_out = hpi * 32 + (n2 >> 3) * 4 + s;
    float gmul = gate[b * 256 + c_out];
    float* outb = out + (size_t)(b * 256 + c_out) * 4096 + cgh * 8 * 64 + (n2 & 7) * 8;
#pragma unroll
    for (int oti = 0; oti < 2; ++oti) {
      f32x4 a = acc[oti][nt];
      int hh = (half * 2 + oti) * 2 + (g >> 1);
      int wo = (g & 1) * 4;
      f32x4 o4 = {(a.x + tb) * gmul, (a.y + tb) * gmul,
                  (a.z + tb) * gmul, (a.w + tb) * gmul};
      __builtin_nontemporal_store(o4, (f32x4*)(outb + hh * 64 + wo));
    }
  }
}

extern "C" void kernel_launch(void* const* d_in, const int* in_sizes, int n_in,
                              void* d_out, int out_size, void* d_ws, size_t ws_size,
                              hipStream_t stream) {
  const float* x     = (const float*)d_in[0];
  const float* fc1_w = (const float*)d_in[1];
  const float* fc1_b = (const float*)d_in[2];
  const float* fc2_w = (const float*)d_in[3];
  const float* fc2_b = (const float*)d_in[4];
  const float* fc3_w = (const float*)d_in[5];
  const float* g3  = (const float*)d_in[6];
  const float* b3  = (const float*)d_in[7];
  const float* m3  = (const float*)d_in[8];
  const float* v3  = (const float*)d_in[9];
  const float* c1w = (const float*)d_in[10];
  const float* g1  = (const float*)d_in[11];
  const float* b1  = (const float*)d_in[12];
  const float* m1  = (const float*)d_in[13];
  const float* v1  = (const float*)d_in[14];
  const float* c3w = (const float*)d_in[15];
  const float* gk  = (const float*)d_in[16];
  const float* bk  = (const float*)d_in[17];
  const float* mk  = (const float*)d_in[18];
  const float* vk  = (const float*)d_in[19];
  float* out = (float*)d_out;

  // ws layout (16B-aligned): pooled 32KB | gate 32KB | ahi 32KB | alo 32KB | totb
  float* pooled = (float*)d_ws;
  float* gate   = pooled + 8192;
  unsigned short* ahi = (unsigned short*)(gate + 8192);
  unsigned short* alo = ahi + 16384;
  float* totb   = (float*)(alo + 16384);

  prep_pool_kernel<<<8208, 256, 0, stream>>>(x, pooled, fc3_w, g3, b3, m3, v3,
                                             c1w, g1, b1, m1, v1, c3w, gk, bk,
                                             mk, vk, ahi, alo, totb);
  gate_kernel<<<32, 256, 0, stream>>>(pooled, fc1_w, fc1_b, fc2_w, fc2_b, gate);
  main_kernel<<<4096, 256, 0, stream>>>(x, ahi, alo, totb, gate, out);
}

// Round 7
// 86.888 us; speedup vs baseline: 1.0061x; 1.0061x over previous
//
#include <hip/hip_runtime.h>
#include <hip/hip_cooperative_groups.h>
#include <hip/hip_bf16.h>
#include <math.h>

namespace cg = cooperative_groups;

#define BN_EPS 1e-5f

typedef __attribute__((ext_vector_type(8))) short short8;
typedef __attribute__((ext_vector_type(4))) float f32x4;

__device__ __forceinline__ unsigned short bfbits(float f) {
  __hip_bfloat16 h = __float2bfloat16(f);
  return *reinterpret_cast<unsigned short*>(&h);
}
__device__ __forceinline__ float bf2f(unsigned short u) {
  union { unsigned v; float f; } c; c.v = ((unsigned)u) << 16;
  return c.f;
}

// ================= Fused cooperative kernel =================
// Grid 1024 x 256thr (4 waves). Block = (b, hpi, sp, cq); 4 units (cgh).
// P0: blocks 0..15 prep A = sc3*W + conv-taps (bf16 hi/lo) + totb.
// P1: pool — wave w reduces planes bid*8 + w*2 + {0,1} (no LDS, no syncs).
// grid.sync()
// P2: per-block gate slice (redundant, cheap).
// P3: R6 GEMM body x4 cgh units; A-frags + gate hoisted.
__global__ __launch_bounds__(256, 4) void fused_kernel(
    const float* __restrict__ x,
    const float* __restrict__ fc1_w, const float* __restrict__ fc1_b,
    const float* __restrict__ fc2_w, const float* __restrict__ fc2_b,
    const float* __restrict__ fc3_w,
    const float* __restrict__ g3, const float* __restrict__ b3,
    const float* __restrict__ m3, const float* __restrict__ v3,
    const float* __restrict__ c1w,
    const float* __restrict__ g1, const float* __restrict__ b1,
    const float* __restrict__ m1, const float* __restrict__ v1,
    const float* __restrict__ c3w,
    const float* __restrict__ gk, const float* __restrict__ bk,
    const float* __restrict__ mk, const float* __restrict__ vk,
    float* __restrict__ pooled, unsigned short* __restrict__ ahi,
    unsigned short* __restrict__ alo, float* __restrict__ totb,
    float* __restrict__ gate_unused, float* __restrict__ out) {
  __shared__ float part[4][64];
  __shared__ float hid[64];

  int bid = blockIdx.x;
  int tid = threadIdx.x;

  // ---- P0: prep (16 blocks) ----
  if (bid < 16) {
    int ps = bid >> 2;
    int o = (bid & 3) * 16 + (tid >> 4);
    int kc = (tid & 15) * 4;
    float sc3 = g3[ps] * rsqrtf(v3[ps] + BN_EPS);
    float sc1 = g1[ps] * rsqrtf(v1[ps] + BN_EPS);
    float sck = gk[ps] * rsqrtf(vk[ps] + BN_EPS);
    float c0 = sc1 * c1w[ps] + sck * c3w[ps * 9 + 4];
    int oh = o >> 3, ow = o & 7;
    unsigned short H[4], L[4];
#pragma unroll
    for (int j = 0; j < 4; ++j) {
      int k = kc + j;
      int kh = k >> 3, kw = k & 7;
      float a = sc3 * fc3_w[(ps * 64 + o) * 64 + k];
      int dy = kh - oh, dx = kw - ow;
      if (dy >= -1 && dy <= 1 && dx >= -1 && dx <= 1)
        a += (dy == 0 && dx == 0) ? c0 : sck * c3w[ps * 9 + (dy + 1) * 3 + (dx + 1)];
      unsigned short h = bfbits(a);
      H[j] = h;
      L[j] = bfbits(a - bf2f(h));
    }
    size_t base = (size_t)(ps * 64 + o) * 64 + kc;
    *(ushort4*)(ahi + base) = make_ushort4(H[0], H[1], H[2], H[3]);
    *(ushort4*)(alo + base) = make_ushort4(L[0], L[1], L[2], L[3]);
    if (bid == 0 && tid < 4) {
      int ss = tid;
      float s3 = g3[ss] * rsqrtf(v3[ss] + BN_EPS);
      float s1 = g1[ss] * rsqrtf(v1[ss] + BN_EPS);
      float sk = gk[ss] * rsqrtf(vk[ss] + BN_EPS);
      totb[ss] = (b3[ss] - m3[ss] * s3) + (b1[ss] - m1[ss] * s1) + (bk[ss] - mk[ss] * sk);
    }
  }

  // ---- P1: pool — wave w: planes bid*8 + w*2 + {0,1} ----
  {
    int w = tid >> 6, lane = tid & 63;
#pragma unroll
    for (int p = 0; p < 2; ++p) {
      int bc = bid * 8 + w * 2 + p;
      const f32x4* xp = (const f32x4*)(x + (size_t)bc * 4096);
      float ssum = 0.f;
#pragma unroll
      for (int i = 0; i < 16; ++i) {
        f32x4 v = xp[i * 64 + lane];
        ssum += (v.x + v.y) + (v.z + v.w);
      }
#pragma unroll
      for (int m = 32; m >= 1; m >>= 1) ssum += __shfl_xor(ssum, m, 64);
      if (lane == 0) pooled[bc] = ssum * (1.f / 4096.f);
    }
  }

  cg::this_grid().sync();

  // ---- decode block coords ----
  int cq  = bid & 1;
  int sp  = (bid >> 1) & 1;
  int hpi = (bid >> 2) & 7;
  int b   = bid >> 5;
  int s    = __builtin_amdgcn_readfirstlane(sp * 2 + ((tid >> 7) & 1));
  int half = __builtin_amdgcn_readfirstlane((tid >> 6) & 1);
  int r16 = tid & 15;
  int g   = (tid >> 4) & 3;

  // ---- P2: gate slice for this block's 16 channels ----
  {
    int hh = tid & 63, q = tid >> 6;
    const float* pb = pooled + b * 256 + q * 64;
    const float* wr = fc1_w + hh * 256 + q * 64;
    float a = 0.f;
#pragma unroll 16
    for (int j = 0; j < 64; ++j) a += pb[j] * wr[j];
    part[q][hh] = a;
  }
  __syncthreads();
  if (tid < 64)
    hid[tid] = fmaxf(part[0][tid] + part[1][tid] + part[2][tid] + part[3][tid] + fc1_b[tid], 0.f);
  __syncthreads();

  float gmul[4];
#pragma unroll
  for (int nt = 0; nt < 4; ++nt) {
    int c_out = hpi * 32 + (nt * 2 + (r16 >> 3)) * 4 + s;
    const float* w2 = fc2_w + c_out * 64;
    float a = fc2_b[c_out];
#pragma unroll 16
    for (int j = 0; j < 64; ++j) a += hid[j] * w2[j];
    gmul[nt] = 1.f / (1.f + expf(-a));
  }

  // ---- P3: GEMM units ----
  float tb = totb[s];

  short8 Ah[2][2], Al[2][2];  // [kt][oti]
#pragma unroll
  for (int oti = 0; oti < 2; ++oti)
#pragma unroll
    for (int kt = 0; kt < 2; ++kt) {
      size_t off = (size_t)(s * 64 + (half * 2 + oti) * 16 + r16) * 64 + kt * 32 + g * 8;
      Ah[kt][oti] = *(const short8*)(ahi + off);
      Al[kt][oti] = *(const short8*)(alo + off);
    }

  for (int u = 0; u < 4; ++u) {
    int cgh = cq * 4 + u;

    f32x4 acc[2][4];
#pragma unroll
    for (int i = 0; i < 2; ++i)
#pragma unroll
      for (int j = 0; j < 4; ++j) acc[i][j] = f32x4{0.f, 0.f, 0.f, 0.f};

#pragma unroll
    for (int kt = 0; kt < 2; ++kt) {
      f32x4 q0[4], q1[4];
#pragma unroll
      for (int nt = 0; nt < 4; ++nt) {
        int n2 = nt * 16 + r16;
        int c_in = (cgh * 8 + (n2 & 7)) * 4 + s;
        const float* bp = x + (size_t)(b * 256 + c_in) * 4096
                          + (hpi * 8 + kt * 4 + g) * 64 + (n2 >> 3) * 8;
        q0[nt] = *(const f32x4*)bp;
        q1[nt] = *(const f32x4*)(bp + 4);
      }
#pragma unroll
      for (int nt = 0; nt < 4; ++nt) {
        float fv[8] = {q0[nt].x, q0[nt].y, q0[nt].z, q0[nt].w,
                       q1[nt].x, q1[nt].y, q1[nt].z, q1[nt].w};
        union { unsigned short u16[8]; short8 v; } BH, BL;
#pragma unroll
        for (int j = 0; j < 8; ++j) {
          unsigned short h = bfbits(fv[j]);
          BH.u16[j] = h;
          BL.u16[j] = bfbits(fv[j] - bf2f(h));
        }
#pragma unroll
        for (int oti = 0; oti < 2; ++oti) {
          acc[oti][nt] = __builtin_amdgcn_mfma_f32_16x16x32_bf16(Ah[kt][oti], BH.v, acc[oti][nt], 0, 0, 0);
          acc[oti][nt] = __builtin_amdgcn_mfma_f32_16x16x32_bf16(Ah[kt][oti], BL.v, acc[oti][nt], 0, 0, 0);
          acc[oti][nt] = __builtin_amdgcn_mfma_f32_16x16x32_bf16(Al[kt][oti], BH.v, acc[oti][nt], 0, 0, 0);
        }
      }
    }

#pragma unroll
    for (int nt = 0; nt < 4; ++nt) {
      int n2 = nt * 16 + r16;
      int c_out = hpi * 32 + (n2 >> 3) * 4 + s;
      float gm = gmul[nt];
      float* outb = out + (size_t)(b * 256 + c_out) * 4096 + cgh * 8 * 64 + (n2 & 7) * 8;
#pragma unroll
      for (int oti = 0; oti < 2; ++oti) {
        f32x4 a = acc[oti][nt];
        int hh = (half * 2 + oti) * 2 + (g >> 1);
        int wo = (g & 1) * 4;
        f32x4 o4 = {(a.x + tb) * gm, (a.y + tb) * gm,
                    (a.z + tb) * gm, (a.w + tb) * gm};
        __builtin_nontemporal_store(o4, (f32x4*)(outb + hh * 64 + wo));
      }
    }
  }
}

// ================= Fallback (3-kernel) path =================
__global__ __launch_bounds__(256) void prep_pool_kernel(
    const float* __restrict__ x, float* __restrict__ pooled,
    const float* __restrict__ fc3_w,
    const float* __restrict__ g3, const float* __restrict__ b3,
    const float* __restrict__ m3, const float* __restrict__ v3,
    const float* __restrict__ c1w,
    const float* __restrict__ g1, const float* __restrict__ b1,
    const float* __restrict__ m1, const float* __restrict__ v1,
    const float* __restrict__ c3w,
    const float* __restrict__ gk, const float* __restrict__ bk,
    const float* __restrict__ mk, const float* __restrict__ vk,
    unsigned short* __restrict__ ahi, unsigned short* __restrict__ alo,
    float* __restrict__ totb) {
  int bid = blockIdx.x;
  int tid = threadIdx.x;
  if (bid < 16) {
    int s = bid >> 2;
    int o = (bid & 3) * 16 + (tid >> 4);
    int kc = (tid & 15) * 4;
    float sc3 = g3[s] * rsqrtf(v3[s] + BN_EPS);
    float sc1 = g1[s] * rsqrtf(v1[s] + BN_EPS);
    float sck = gk[s] * rsqrtf(vk[s] + BN_EPS);
    float c0 = sc1 * c1w[s] + sck * c3w[s * 9 + 4];
    int oh = o >> 3, ow = o & 7;
    unsigned short H[4], L[4];
#pragma unroll
    for (int j = 0; j < 4; ++j) {
      int k = kc + j;
      int kh = k >> 3, kw = k & 7;
      float a = sc3 * fc3_w[(s * 64 + o) * 64 + k];
      int dy = kh - oh, dx = kw - ow;
      if (dy >= -1 && dy <= 1 && dx >= -1 && dx <= 1)
        a += (dy == 0 && dx == 0) ? c0 : sck * c3w[s * 9 + (dy + 1) * 3 + (dx + 1)];
      unsigned short h = bfbits(a);
      H[j] = h;
      L[j] = bfbits(a - bf2f(h));
    }
    size_t base = (size_t)(s * 64 + o) * 64 + kc;
    *(ushort4*)(ahi + base) = make_ushort4(H[0], H[1], H[2], H[3]);
    *(ushort4*)(alo + base) = make_ushort4(L[0], L[1], L[2], L[3]);
    if (bid == 0 && tid < 4) {
      int ss = tid;
      float s3 = g3[ss] * rsqrtf(v3[ss] + BN_EPS);
      float s1 = g1[ss] * rsqrtf(v1[ss] + BN_EPS);
      float sk = gk[ss] * rsqrtf(vk[ss] + BN_EPS);
      totb[ss] = (b3[ss] - m3[ss] * s3) + (b1[ss] - m1[ss] * s1) + (bk[ss] - mk[ss] * sk);
    }
    return;
  }
  int bc = bid - 16;
  const float4* xp = reinterpret_cast<const float4*>(x + (size_t)bc * 4096);
  float s = 0.f;
#pragma unroll
  for (int k = 0; k < 4; ++k) {
    float4 v = xp[k * 256 + tid];
    s += (v.x + v.y) + (v.z + v.w);
  }
#pragma unroll
  for (int m = 32; m >= 1; m >>= 1) s += __shfl_xor(s, m, 64);
  __shared__ float wsum[4];
  if ((tid & 63) == 0) wsum[tid >> 6] = s;
  __syncthreads();
  if (tid == 0) pooled[bc] = (wsum[0] + wsum[1] + wsum[2] + wsum[3]) * (1.f / 4096.f);
}

__global__ __launch_bounds__(256) void gate_kernel(const float* __restrict__ pooled,
                                                   const float* __restrict__ fc1_w,
                                                   const float* __restrict__ fc1_b,
                                                   const float* __restrict__ fc2_w,
                                                   const float* __restrict__ fc2_b,
                                                   float* __restrict__ gate) {
  int b = blockIdx.x;
  int tid = threadIdx.x;
  __shared__ float p[256];
  __shared__ float hbuf[64];
  p[tid] = pooled[b * 256 + tid];
  __syncthreads();
  if (tid < 64) {
    float a = fc1_b[tid];
    const float* wr = fc1_w + tid * 256;
#pragma unroll 8
    for (int c = 0; c < 256; ++c) a += p[c] * wr[c];
    hbuf[tid] = fmaxf(a, 0.f);
  }
  __syncthreads();
  float g = fc2_b[tid];
  const float* w2 = fc2_w + tid * 64;
#pragma unroll 8
  for (int j = 0; j < 64; ++j) g += hbuf[j] * w2[j];
  gate[b * 256 + tid] = 1.f / (1.f + expf(-g));
}

__global__ __launch_bounds__(256, 4) void main_kernel(
    const float* __restrict__ x,
    const unsigned short* __restrict__ ahi, const unsigned short* __restrict__ alo,
    const float* __restrict__ totb, const float* __restrict__ gate,
    float* __restrict__ out) {
  int bid = blockIdx.x;
  int sp  = bid & 1;
  int cgh = (bid >> 1) & 7;
  int hpi = (bid >> 4) & 7;
  int b   = bid >> 7;
  int tid = threadIdx.x;
  int s    = __builtin_amdgcn_readfirstlane(sp * 2 + ((tid >> 7) & 1));
  int half = __builtin_amdgcn_readfirstlane((tid >> 6) & 1);
  int r16 = tid & 15;
  int g   = (tid >> 4) & 3;
  float tb = totb[s];
  short8 Ah[2][2], Al[2][2];
#pragma unroll
  for (int oti = 0; oti < 2; ++oti)
#pragma unroll
    for (int kt = 0; kt < 2; ++kt) {
      size_t off = (size_t)(s * 64 + (half * 2 + oti) * 16 + r16) * 64 + kt * 32 + g * 8;
      Ah[kt][oti] = *(const short8*)(ahi + off);
      Al[kt][oti] = *(const short8*)(alo + off);
    }
  f32x4 acc[2][4];
#pragma unroll
  for (int i = 0; i < 2; ++i)
#pragma unroll
    for (int j = 0; j < 4; ++j) acc[i][j] = f32x4{0.f, 0.f, 0.f, 0.f};
#pragma unroll
  for (int kt = 0; kt < 2; ++kt) {
    f32x4 q0[4], q1[4];
#pragma unroll
    for (int nt = 0; nt < 4; ++nt) {
      int n2 = nt * 16 + r16;
      int c_in = (cgh * 8 + (n2 & 7)) * 4 + s;
      const float* bp = x + (size_t)(b * 256 + c_in) * 4096
                        + (hpi * 8 + kt * 4 + g) * 64 + (n2 >> 3) * 8;
      q0[nt] = *(const f32x4*)bp;
      q1[nt] = *(const f32x4*)(bp + 4);
    }
#pragma unroll
    for (int nt = 0; nt < 4; ++nt) {
      float fv[8] = {q0[nt].x, q0[nt].y, q0[nt].z, q0[nt].w,
                     q1[nt].x, q1[nt].y, q1[nt].z, q1[nt].w};
      union { unsigned short u[8]; short8 v; } BH, BL;
#pragma unroll
      for (int j = 0; j < 8; ++j) {
        unsigned short h = bfbits(fv[j]);
        BH.u[j] = h;
        BL.u[j] = bfbits(fv[j] - bf2f(h));
      }
#pragma unroll
      for (int oti = 0; oti < 2; ++oti) {
        acc[oti][nt] = __builtin_amdgcn_mfma_f32_16x16x32_bf16(Ah[kt][oti], BH.v, acc[oti][nt], 0, 0, 0);
        acc[oti][nt] = __builtin_amdgcn_mfma_f32_16x16x32_bf16(Ah[kt][oti], BL.v, acc[oti][nt], 0, 0, 0);
        acc[oti][nt] = __builtin_amdgcn_mfma_f32_16x16x32_bf16(Al[kt][oti], BH.v, acc[oti][nt], 0, 0, 0);
      }
    }
  }
#pragma unroll
  for (int nt = 0; nt < 4; ++nt) {
    int n2 = nt * 16 + r16;
    int c_out = hpi * 32 + (n2 >> 3) * 4 + s;
    float gmul = gate[b * 256 + c_out];
    float* outb = out + (size_t)(b * 256 + c_out) * 4096 + cgh * 8 * 64 + (n2 & 7) * 8;
#pragma unroll
    for (int oti = 0; oti < 2; ++oti) {
      f32x4 a = acc[oti][nt];
      int hh = (half * 2 + oti) * 2 + (g >> 1);
      int wo = (g & 1) * 4;
      f32x4 o4 = {(a.x + tb) * gmul, (a.y + tb) * gmul,
                  (a.z + tb) * gmul, (a.w + tb) * gmul};
      __builtin_nontemporal_store(o4, (f32x4*)(outb + hh * 64 + wo));
    }
  }
}

extern "C" void kernel_launch(void* const* d_in, const int* in_sizes, int n_in,
                              void* d_out, int out_size, void* d_ws, size_t ws_size,
                              hipStream_t stream) {
  const float* x     = (const float*)d_in[0];
  const float* fc1_w = (const float*)d_in[1];
  const float* fc1_b = (const float*)d_in[2];
  const float* fc2_w = (const float*)d_in[3];
  const float* fc2_b = (const float*)d_in[4];
  const float* fc3_w = (const float*)d_in[5];
  const float* g3  = (const float*)d_in[6];
  const float* b3  = (const float*)d_in[7];
  const float* m3  = (const float*)d_in[8];
  const float* v3  = (const float*)d_in[9];
  const float* c1w = (const float*)d_in[10];
  const float* g1  = (const float*)d_in[11];
  const float* b1  = (const float*)d_in[12];
  const float* m1  = (const float*)d_in[13];
  const float* v1  = (const float*)d_in[14];
  const float* c3w = (const float*)d_in[15];
  const float* gk  = (const float*)d_in[16];
  const float* bk  = (const float*)d_in[17];
  const float* mk  = (const float*)d_in[18];
  const float* vk  = (const float*)d_in[19];
  float* out = (float*)d_out;

  float* pooled = (float*)d_ws;
  float* gate   = pooled + 8192;
  unsigned short* ahi = (unsigned short*)(gate + 8192);
  unsigned short* alo = ahi + 16384;
  float* totb   = (float*)(alo + 16384);

  int maxB = 0;
  hipOccupancyMaxActiveBlocksPerMultiprocessor(&maxB, fused_kernel, 256, 0);
  if (maxB >= 4) {
    void* args[] = {
      (void*)&x, (void*)&fc1_w, (void*)&fc1_b, (void*)&fc2_w, (void*)&fc2_b,
      (void*)&fc3_w, (void*)&g3, (void*)&b3, (void*)&m3, (void*)&v3,
      (void*)&c1w, (void*)&g1, (void*)&b1, (void*)&m1, (void*)&v1,
      (void*)&c3w, (void*)&gk, (void*)&bk, (void*)&mk, (void*)&vk,
      (void*)&pooled, (void*)&ahi, (void*)&alo, (void*)&totb,
      (void*)&gate, (void*)&out,
    };
    hipLaunchCooperativeKernel((void*)fused_kernel, dim3(1024), dim3(256),
                               args, 0, stream);
  } else {
    prep_pool_kernel<<<8208, 256, 0, stream>>>(x, pooled, fc3_w, g3, b3, m3, v3,
                                               c1w, g1, b1, m1, v1, c3w, gk, bk,
                                               mk, vk, ahi, alo, totb);
    gate_kernel<<<32, 256, 0, stream>>>(pooled, fc1_w, fc1_b, fc2_w, fc2_b, gate);
    main_kernel<<<4096, 256, 0, stream>>>(x, ahi, alo, totb, gate, out);
  }
}